// Round 1
// baseline (249.825 us; speedup 1.0000x reference)
//
#include <hip/hip_runtime.h>
#include <hip/hip_bf16.h>
#include <stdint.h>

// ---------------------------------------------------------------------------
// Net_71373766525077: SNN leaky layer.
//   cur = x @ W^T   (1024x4096 @ 4096x4096, fp32 in, tolerance ~2% -> bf16 MFMA)
//   scan over t: reset=(mem>1); mem=0.9*mem+cur[t]-reset; spk=(mem>1)
//   out = concat(spk_rec, mem_rec)  fp32
// ---------------------------------------------------------------------------

typedef __attribute__((ext_vector_type(8))) short bf16x8;
typedef __attribute__((ext_vector_type(4))) float floatx4;

#define T_STEPS 1024
#define N_IN    4096
#define N_OUT   4096

#define BM 128
#define BN 128
#define BKK 64   // K-chunk (bf16 elements)

__device__ __forceinline__ unsigned short f2bf_rne(float f) {
    unsigned int u = __builtin_bit_cast(unsigned int, f);
    unsigned int r = 0x7FFFu + ((u >> 16) & 1u);
    return (unsigned short)((u + r) >> 16);
}

// fp32 -> bf16 convert, float4 / ushort4 vectorized. n4 = count of float4s.
__global__ __launch_bounds__(256) void cvt_kernel(const float4* __restrict__ in,
                                                  ushort4* __restrict__ out, int n4) {
    int i = blockIdx.x * blockDim.x + threadIdx.x;
    if (i < n4) {
        float4 v = in[i];
        ushort4 o;
        o.x = f2bf_rne(v.x);
        o.y = f2bf_rne(v.y);
        o.z = f2bf_rne(v.z);
        o.w = f2bf_rne(v.w);
        out[i] = o;
    }
}

__device__ __forceinline__ void gload16(const void* g, void* l) {
    __builtin_amdgcn_global_load_lds((const __attribute__((address_space(1))) void*)g,
                                     (__attribute__((address_space(3))) void*)l,
                                     16, 0, 0);
}

// C[M][N] = A[M][K] * B[N][K]^T, A/B bf16 (as short bits), C fp32.
// 128x128 tile per block, 256 threads = 4 waves in 2x2 grid, each wave 64x64
// via 4x4 of 16x16x32 MFMA. Single-buffered LDS, global_load_lds width 16.
__global__ __launch_bounds__(256) void gemm_bt(const short* __restrict__ A,
                                               const short* __restrict__ B,
                                               float* __restrict__ C,
                                               int M, int N, int K) {
    __shared__ short sA[BM * BKK];  // [128][64] row-major, 16 KB
    __shared__ short sB[BN * BKK];  // [128][64] row-major, 16 KB

    const int tid  = threadIdx.x;
    const int lane = tid & 63;
    const int wv   = tid >> 6;       // 0..3
    const int wm   = (wv & 1) * 64;  // wave m-offset in tile
    const int wn   = (wv >> 1) * 64; // wave n-offset in tile
    const long bm  = (long)blockIdx.y * BM;
    const long bn  = (long)blockIdx.x * BN;

    floatx4 acc[4][4] = {};

    // Staging: tile row = 64 bf16 = 128 B. Thread tid covers bytes
    // [p*4096 + tid*16, +16) of the tile, p = 0..3  (4 passes * 4 KB = 16 KB).
    const int srow = tid >> 3;        // 0..31 (row within pass)
    const int scol = (tid & 7) * 8;   // bf16 offset within row
    const short* gA[4];
    const short* gB[4];
    short* lA[4];
    short* lB[4];
#pragma unroll
    for (int p = 0; p < 4; ++p) {
        gA[p] = A + (bm + p * 32 + srow) * (long)K + scol;
        gB[p] = B + (bn + p * 32 + srow) * (long)K + scol;
        lA[p] = sA + p * 2048 + tid * 8;   // shorts; lane0-of-wave value is the base
        lB[p] = sB + p * 2048 + tid * 8;
    }

    const int fm  = lane & 15;        // A-row / B-col within 16
    const int fko = (lane >> 4) * 8;  // k element offset (0,8,16,24)

    for (int k0 = 0; k0 < K; k0 += BKK) {
#pragma unroll
        for (int p = 0; p < 4; ++p) gload16(gA[p] + k0, lA[p]);
#pragma unroll
        for (int p = 0; p < 4; ++p) gload16(gB[p] + k0, lB[p]);
        __syncthreads();   // compiler emits s_waitcnt vmcnt(0) before barrier

#pragma unroll
        for (int ks = 0; ks < 2; ++ks) {
            bf16x8 af[4], bfr[4];
#pragma unroll
            for (int i = 0; i < 4; ++i)
                af[i] = *(const bf16x8*)(sA + (wm + i * 16 + fm) * 64 + ks * 32 + fko);
#pragma unroll
            for (int j = 0; j < 4; ++j)
                bfr[j] = *(const bf16x8*)(sB + (wn + j * 16 + fm) * 64 + ks * 32 + fko);
#pragma unroll
            for (int i = 0; i < 4; ++i)
#pragma unroll
                for (int j = 0; j < 4; ++j)
                    acc[i][j] = __builtin_amdgcn_mfma_f32_16x16x32_bf16(
                        af[i], bfr[j], acc[i][j], 0, 0, 0);
        }
        __syncthreads();
    }

    // Epilogue: C/D layout col=lane&15, row=(lane>>4)*4+reg  [m89/m91 verified]
    const int cn = lane & 15;
    const int cm = (lane >> 4) * 4;
#pragma unroll
    for (int i = 0; i < 4; ++i)
#pragma unroll
        for (int j = 0; j < 4; ++j)
#pragma unroll
            for (int r = 0; r < 4; ++r)
                C[(bm + wm + i * 16 + cm + r) * (long)N + (bn + wn + j * 16 + cn)] =
                    acc[i][j][r];
}

// One thread per neuron. cur is t-major [T][N] so lanes are coalesced.
// Double-buffered register prefetch of U=32 timesteps to hide HBM latency
// (only 64 waves of parallelism exist: 4096 chains).
#define SCAN_U 32
__global__ __launch_bounds__(64) void scan_kernel(const float* __restrict__ cur,
                                                  float* __restrict__ out) {
    const int o = blockIdx.x * 64 + threadIdx.x;  // neuron 0..4095
    float* __restrict__ spk = out;
    float* __restrict__ memo = out + (size_t)T_STEPS * N_OUT;

    float mem = 0.0f;
    float b0[SCAN_U], b1[SCAN_U];
    const float* p = cur + o;

#pragma unroll
    for (int j = 0; j < SCAN_U; ++j) b0[j] = p[(size_t)j * N_OUT];

    for (int t0 = 0; t0 < T_STEPS; t0 += 2 * SCAN_U) {
#pragma unroll
        for (int j = 0; j < SCAN_U; ++j) b1[j] = p[(size_t)(t0 + SCAN_U + j) * N_OUT];
#pragma unroll
        for (int j = 0; j < SCAN_U; ++j) {
            float rst = mem > 1.0f ? 1.0f : 0.0f;
            mem = 0.9f * mem + b0[j] - rst;
            float s = mem > 1.0f ? 1.0f : 0.0f;
            size_t idx = (size_t)(t0 + j) * N_OUT + o;
            spk[idx] = s;
            memo[idx] = mem;
        }
        const int tn = (t0 + 2 * SCAN_U < T_STEPS) ? (t0 + 2 * SCAN_U) : 0;  // dummy on last iter
#pragma unroll
        for (int j = 0; j < SCAN_U; ++j) b0[j] = p[(size_t)(tn + j) * N_OUT];
#pragma unroll
        for (int j = 0; j < SCAN_U; ++j) {
            float rst = mem > 1.0f ? 1.0f : 0.0f;
            mem = 0.9f * mem + b1[j] - rst;
            float s = mem > 1.0f ? 1.0f : 0.0f;
            size_t idx = (size_t)(t0 + SCAN_U + j) * N_OUT + o;
            spk[idx] = s;
            memo[idx] = mem;
        }
    }
}

extern "C" void kernel_launch(void* const* d_in, const int* in_sizes, int n_in,
                              void* d_out, int out_size, void* d_ws, size_t ws_size,
                              hipStream_t stream) {
    const float* x = (const float*)d_in[0];  // [1024][4096]
    const float* W = (const float*)d_in[1];  // [4096][4096]
    float* out = (float*)d_out;              // [2][1024][4096]

    char* ws = (char*)d_ws;
    short* xb  = (short*)ws;                                          // 8 MB bf16
    short* Wb  = (short*)(ws + (size_t)T_STEPS * N_IN * 2);           // 33.6 MB bf16
    float* cur = (float*)(ws + (size_t)T_STEPS * N_IN * 2
                             + (size_t)N_OUT * N_IN * 2);             // 16.8 MB fp32

    // 1) fp32 -> bf16 converts
    {
        int n4 = T_STEPS * N_IN / 4;
        cvt_kernel<<<n4 / 256, 256, 0, stream>>>((const float4*)x, (ushort4*)xb, n4);
    }
    {
        int n4 = N_OUT * N_IN / 4;
        cvt_kernel<<<n4 / 256, 256, 0, stream>>>((const float4*)W, (ushort4*)Wb, n4);
    }

    // 2) cur = x @ W^T  (bf16 MFMA, fp32 accumulate)
    gemm_bt<<<dim3(N_OUT / BN, T_STEPS / BM), 256, 0, stream>>>(
        xb, Wb, cur, T_STEPS, N_OUT, N_IN);

    // 3) sequential membrane scan + spike emit
    scan_kernel<<<N_OUT / 64, 64, 0, stream>>>(cur, out);
}